// Round 3
// baseline (669.146 us; speedup 1.0000x reference)
//
#include <hip/hip_runtime.h>
#include <math.h>

#define T_TOKENS 16384
#define D_DIM    2048
#define NEXP     256
#define TOPK     8
#define NLIM     4
#define BM       64
#define BK       32
#define KSTEPS   (D_DIM / BK)   // 64
#define NTHREADS 256

typedef __attribute__((ext_vector_type(8))) short bf16x8;   // 8 bf16 (4 VGPRs)
typedef __attribute__((ext_vector_type(4))) float f32x4;    // MFMA acc

// LDS plan (union, ~120 KB -> 1 block/CU):
//  A[2][3][4][64][8]  bf16 : x splits, fragment-linear   24576 B
//  B[2][3][16][64][8] bf16 : w splits, fragment-linear   98304 B
//  Sc[64][256] f32 : logits->scores for routing (aliases A/B)
struct GemmBufs {
  unsigned short A[2][3][4][64][8];
  unsigned short B[2][3][16][64][8];
};
union SMem {
  GemmBufs g;
  float Sc[BM][NEXP];
};
static_assert(sizeof(SMem) <= 131072, "LDS budget");

__device__ inline unsigned short f2bf(float f) {   // RTN-even, finite inputs
  union { float f; unsigned u; } v; v.f = f;
  unsigned r = v.u + 0x7FFFu + ((v.u >> 16) & 1u);
  return (unsigned short)(r >> 16);
}
__device__ inline float bf2f(unsigned short h) {
  union { unsigned u; float f; } v; v.u = ((unsigned)h) << 16;
  return v.f;
}
__device__ inline void split3(float f, unsigned short& a, unsigned short& b,
                              unsigned short& c) {
  a = f2bf(f); float r = f - bf2f(a);
  b = f2bf(r); r -= bf2f(b);
  c = f2bf(r);
}

union Pack8 { unsigned short s[8]; float4 v; };

// ---- pre-pass: w[256][2048] f32 -> 3 bf16 splits in MFMA-fragment order ----
// wf layout (bf16 elems): [ks(64)][split(3)][nfg(16)][lane(64)][j(8)]
// value = split_s( w[ e = nfg*16 + (lane&15) ][ k = ks*32 + (lane>>4)*8 + j ] )
__global__ __launch_bounds__(256) void prep_w(const float* __restrict__ w,
                                              unsigned short* __restrict__ wf) {
  const int g   = blockIdx.x * 256 + threadIdx.x;  // 0..65535
  const int ks  = g >> 10;
  const int rem = g & 1023;
  const int nfg = rem >> 6;
  const int l   = rem & 63;
  const int e   = nfg * 16 + (l & 15);
  const int kb  = ks * 32 + ((l >> 4) << 3);
  const float* src = &w[(size_t)e * D_DIM + kb];
  float f[8];
  *reinterpret_cast<float4*>(&f[0]) = *reinterpret_cast<const float4*>(src);
  *reinterpret_cast<float4*>(&f[4]) = *reinterpret_cast<const float4*>(src + 4);
  Pack8 h[3];
  #pragma unroll
  for (int j = 0; j < 8; ++j) split3(f[j], h[0].s[j], h[1].s[j], h[2].s[j]);
  const size_t base = (size_t)ks * 24576 + (size_t)nfg * 512 + (size_t)l * 8;
  #pragma unroll
  for (int s = 0; s < 3; ++s)
    *reinterpret_cast<float4*>(wf + base + (size_t)s * 8192) = h[s].v;
}

// ---- fused GEMM (bf16x3 MFMA) + softmax + group-limited top-k routing ----
__global__ __launch_bounds__(NTHREADS, 1) void gate_kernel(
    const float* __restrict__ x,
    const unsigned short* __restrict__ wf,
    const float* __restrict__ bias,
    float* __restrict__ out_w,
    float* __restrict__ out_idx,
    float* __restrict__ out_load) {

  __shared__ SMem sm;
  const int tid  = threadIdx.x;
  const int row0 = blockIdx.x * BM;
  const int lane = tid & 63;
  const int wid  = tid >> 6;       // 0..3
  const int wr   = wid >> 1;       // wave row (32 tokens)
  const int wc   = wid & 1;        // wave col (128 experts)

  // staging map: thread -> (row, 8 consecutive k) of the x tile
  const int srow  = tid >> 2;             // 0..63
  const int skq   = (tid & 3) << 3;       // 0,8,16,24
  const float* xp = &x[(size_t)(row0 + srow) * D_DIM + skq];
  const int s_mfg  = srow >> 4;
  const int s_slot = (srow & 15) | ((skq >> 3) << 4);

  f32x4 acc[2][8];
  #pragma unroll
  for (int i = 0; i < 2; ++i)
    #pragma unroll
    for (int j = 0; j < 8; ++j)
      acc[i][j] = (f32x4)(0.0f);

  float4 xv0, xv1;
  float4 bst[12];

  // ---- prologue: load + stage k-step 0
  xv0 = *reinterpret_cast<const float4*>(xp);
  xv1 = *reinterpret_cast<const float4*>(xp + 4);
  #pragma unroll
  for (int c = 0; c < 12; ++c)
    bst[c] = *reinterpret_cast<const float4*>(wf + (size_t)(c * 256 + tid) * 8);
  {
    float xf[8];
    *reinterpret_cast<float4*>(&xf[0]) = xv0;
    *reinterpret_cast<float4*>(&xf[4]) = xv1;
    Pack8 h[3];
    #pragma unroll
    for (int j = 0; j < 8; ++j) split3(xf[j], h[0].s[j], h[1].s[j], h[2].s[j]);
    #pragma unroll
    for (int s = 0; s < 3; ++s)
      *reinterpret_cast<float4*>(&sm.g.A[0][s][s_mfg][s_slot][0]) = h[s].v;
    unsigned short* bb = &sm.g.B[0][0][0][0][0];
    #pragma unroll
    for (int c = 0; c < 12; ++c)
      *reinterpret_cast<float4*>(bb + (size_t)(c * 256 + tid) * 8) = bst[c];
  }
  __syncthreads();

  int cur = 0;
  for (int ks = 0; ks < KSTEPS; ++ks) {
    const bool more = (ks + 1 < KSTEPS);
    // issue next-step global loads early (hide under MFMA)
    if (more) {
      const float* xn = xp + (ks + 1) * BK;
      xv0 = *reinterpret_cast<const float4*>(xn);
      xv1 = *reinterpret_cast<const float4*>(xn + 4);
      const unsigned short* wn = wf + (size_t)(ks + 1) * 24576;
      #pragma unroll
      for (int c = 0; c < 12; ++c)
        bst[c] = *reinterpret_cast<const float4*>(wn + (size_t)(c * 256 + tid) * 8);
    }

    // ---- compute current buffer: 6 split-products per (mf,nf)
    {
      bf16x8 a[2][3];
      #pragma unroll
      for (int mf = 0; mf < 2; ++mf)
        #pragma unroll
        for (int s = 0; s < 3; ++s)
          a[mf][s] = *reinterpret_cast<const bf16x8*>(
              &sm.g.A[cur][s][wr * 2 + mf][lane][0]);
      #pragma unroll
      for (int nf = 0; nf < 8; ++nf) {
        const int nfg = wc * 8 + nf;
        bf16x8 b0 = *reinterpret_cast<const bf16x8*>(&sm.g.B[cur][0][nfg][lane][0]);
        bf16x8 b1 = *reinterpret_cast<const bf16x8*>(&sm.g.B[cur][1][nfg][lane][0]);
        bf16x8 b2 = *reinterpret_cast<const bf16x8*>(&sm.g.B[cur][2][nfg][lane][0]);
        #pragma unroll
        for (int mf = 0; mf < 2; ++mf) {
          f32x4 c = acc[mf][nf];
          c = __builtin_amdgcn_mfma_f32_16x16x32_bf16(a[mf][1], b1, c, 0, 0, 0);
          c = __builtin_amdgcn_mfma_f32_16x16x32_bf16(a[mf][2], b0, c, 0, 0, 0);
          c = __builtin_amdgcn_mfma_f32_16x16x32_bf16(a[mf][0], b2, c, 0, 0, 0);
          c = __builtin_amdgcn_mfma_f32_16x16x32_bf16(a[mf][0], b1, c, 0, 0, 0);
          c = __builtin_amdgcn_mfma_f32_16x16x32_bf16(a[mf][1], b0, c, 0, 0, 0);
          c = __builtin_amdgcn_mfma_f32_16x16x32_bf16(a[mf][0], b0, c, 0, 0, 0);
          acc[mf][nf] = c;
        }
      }
    }

    // ---- stage next step into the other buffer
    if (more) {
      const int nxt = cur ^ 1;
      float xf[8];
      *reinterpret_cast<float4*>(&xf[0]) = xv0;
      *reinterpret_cast<float4*>(&xf[4]) = xv1;
      Pack8 h[3];
      #pragma unroll
      for (int j = 0; j < 8; ++j) split3(xf[j], h[0].s[j], h[1].s[j], h[2].s[j]);
      #pragma unroll
      for (int s = 0; s < 3; ++s)
        *reinterpret_cast<float4*>(&sm.g.A[nxt][s][s_mfg][s_slot][0]) = h[s].v;
      unsigned short* bb = &sm.g.B[nxt][0][0][0][0];
      #pragma unroll
      for (int c = 0; c < 12; ++c)
        *reinterpret_cast<float4*>(bb + (size_t)(c * 256 + tid) * 8) = bst[c];
    }
    __syncthreads();
    cur ^= 1;
  }

  // ---- epilogue: logits -> Sc (C/D layout: col=lane&15, row=(lane>>4)*4+r)
  #pragma unroll
  for (int mf = 0; mf < 2; ++mf)
    #pragma unroll
    for (int nf = 0; nf < 8; ++nf)
      #pragma unroll
      for (int r = 0; r < 4; ++r) {
        const int row = wr * 32 + mf * 16 + ((lane >> 4) << 2) + r;
        const int col = wc * 128 + nf * 16 + (lane & 15);
        sm.Sc[row][col] = acc[mf][nf][r];
      }
  __syncthreads();

  // ---- routing: one wave per token, lane holds experts 4l..4l+3
  const float4 bsl = *reinterpret_cast<const float4*>(&bias[lane * 4]);
  const int g = lane >> 3;   // group of this lane's experts

  for (int m = wid; m < BM; m += 4) {
    float v[4];
    *reinterpret_cast<float4*>(v) =
        *reinterpret_cast<const float4*>(&sm.Sc[m][lane * 4]);

    // softmax (match jax: subtract row max, exp, divide by sum)
    float mx = fmaxf(fmaxf(v[0], v[1]), fmaxf(v[2], v[3]));
    #pragma unroll
    for (int s = 1; s < 64; s <<= 1) mx = fmaxf(mx, __shfl_xor(mx, s));
    float ex[4], sum = 0.f;
    #pragma unroll
    for (int j = 0; j < 4; ++j) { ex[j] = expf(v[j] - mx); sum += ex[j]; }
    #pragma unroll
    for (int s = 1; s < 64; s <<= 1) sum += __shfl_xor(sum, s);
    float sc[4], sel[4];
    sc[0] = ex[0] / sum; sc[1] = ex[1] / sum;
    sc[2] = ex[2] / sum; sc[3] = ex[3] / sum;
    sel[0] = sc[0] + bsl.x; sel[1] = sc[1] + bsl.y;
    sel[2] = sc[2] + bsl.z; sel[3] = sc[3] + bsl.w;

    // keep original scores for the gather
    *reinterpret_cast<float4*>(&sm.Sc[m][lane * 4]) =
        make_float4(sc[0], sc[1], sc[2], sc[3]);

    // group max (groups of 32 experts = 8 lanes)
    float gv = fmaxf(fmaxf(sel[0], sel[1]), fmaxf(sel[2], sel[3]));
    gv = fmaxf(gv, __shfl_xor(gv, 1));
    gv = fmaxf(gv, __shfl_xor(gv, 2));
    gv = fmaxf(gv, __shfl_xor(gv, 4));

    // top-4 groups, tie -> lower group index (jax.lax.top_k stability)
    unsigned gmask = 0;
    float gcur = gv;
    #pragma unroll
    for (int it = 0; it < NLIM; ++it) {
      float bv2 = gcur; int bi = g;
      #pragma unroll
      for (int s = 1; s < 64; s <<= 1) {
        float ov = __shfl_xor(bv2, s);
        int   oi = __shfl_xor(bi, s);
        if (ov > bv2 || (ov == bv2 && oi < bi)) { bv2 = ov; bi = oi; }
      }
      gmask |= 1u << bi;
      if (g == bi) gcur = -INFINITY;
    }
    if (!((gmask >> g) & 1u)) {
      sel[0] = sel[1] = sel[2] = sel[3] = -INFINITY;
    }

    // top-8 experts, tie -> lower expert index
    const int gtok = row0 + m;
    #pragma unroll
    for (int it = 0; it < TOPK; ++it) {
      float bv2 = sel[0]; int bi = lane * 4;
      #pragma unroll
      for (int j = 1; j < 4; ++j)
        if (sel[j] > bv2) { bv2 = sel[j]; bi = lane * 4 + j; }
      #pragma unroll
      for (int s = 1; s < 64; s <<= 1) {
        float ov = __shfl_xor(bv2, s);
        int   oi = __shfl_xor(bi, s);
        if (ov > bv2 || (ov == bv2 && oi < bi)) { bv2 = ov; bi = oi; }
      }
      if (lane == 0) {
        out_w[(size_t)gtok * TOPK + it]   = sm.Sc[m][bi] * 2.5f;
        out_idx[(size_t)gtok * TOPK + it] = (float)bi;
        atomicAdd(&out_load[bi], 1.0f);
      }
      if ((bi >> 2) == lane) sel[bi & 3] = -INFINITY;
    }
  }
}

extern "C" void kernel_launch(void* const* d_in, const int* in_sizes, int n_in,
                              void* d_out, int out_size, void* d_ws, size_t ws_size,
                              hipStream_t stream) {
  const float* x    = (const float*)d_in[0];
  const float* w    = (const float*)d_in[1];
  const float* bias = (const float*)d_in[2];
  float* out_w    = (float*)d_out;
  float* out_idx  = out_w + (size_t)T_TOKENS * TOPK;
  float* out_load = out_idx + (size_t)T_TOKENS * TOPK;
  unsigned short* wfrag = (unsigned short*)d_ws;   // 3 MB fragment-ordered w splits

  hipMemsetAsync(out_load, 0, NEXP * sizeof(float), stream);
  prep_w<<<256, 256, 0, stream>>>(w, wfrag);
  gate_kernel<<<T_TOKENS / BM, NTHREADS, 0, stream>>>(
      x, wfrag, bias, out_w, out_idx, out_load);
}

// Round 4
// 256.856 us; speedup vs baseline: 2.6051x; 2.6051x over previous
//
#include <hip/hip_runtime.h>
#include <math.h>

#define T_TOKENS 16384
#define D_DIM    2048
#define NEXP     256
#define TOPK     8
#define NLIM     4
#define BM       64
#define BK       32
#define KSTEPS   (D_DIM / BK)   // 64
#define NTHREADS 512

typedef __attribute__((ext_vector_type(8))) short bf16x8;   // 8 bf16 (4 VGPRs)
typedef __attribute__((ext_vector_type(4))) float f32x4;    // MFMA acc

// LDS plan (union, ~90 KB -> 1 block/CU, 8 waves = 2/SIMD):
//  A[2][3][4][64][8]  bf16 : x splits (3), fragment-linear   24576 B
//  B[2][2][16][64][8] bf16 : w splits s=0,1 (gll dest)       65536 B
//  Sc[64][256] f32 : logits->scores for routing (aliases A/B)
struct GemmBufs {
  unsigned short A[2][3][4][64][8];
  unsigned short B[2][2][16][64][8];
};
union SMem {
  GemmBufs g;
  float Sc[BM][NEXP];
};
static_assert(sizeof(SMem) == 90112, "LDS budget");

__device__ inline unsigned short f2bf(float f) {   // RTN-even, finite inputs
  union { float f; unsigned u; } v; v.f = f;
  unsigned r = v.u + 0x7FFFu + ((v.u >> 16) & 1u);
  return (unsigned short)(r >> 16);
}
__device__ inline float bf2f(unsigned short h) {
  union { unsigned u; float f; } v; v.u = ((unsigned)h) << 16;
  return v.f;
}
__device__ inline void split3(float f, unsigned short& a, unsigned short& b,
                              unsigned short& c) {
  a = f2bf(f); float r = f - bf2f(a);
  b = f2bf(r); r -= bf2f(b);
  c = f2bf(r);
}

union Pack4 { unsigned short s[4]; float2 v; };

typedef __attribute__((address_space(1))) const unsigned short g_ushort;
typedef __attribute__((address_space(3))) unsigned short l_ushort;

// ---- pre-pass: w[256][2048] f32 -> 3 bf16 splits in MFMA-fragment order ----
// wf layout (bf16 elems): [ks(64)][split(3)][nfg(16)][lane(64)][j(8)]
// value = split_s( w[ e = nfg*16 + (lane&15) ][ k = ks*32 + (lane>>4)*8 + j ] )
__global__ __launch_bounds__(256) void prep_w(const float* __restrict__ w,
                                              unsigned short* __restrict__ wf) {
  const int g   = blockIdx.x * 256 + threadIdx.x;  // 0..65535
  const int ks  = g >> 10;
  const int rem = g & 1023;
  const int nfg = rem >> 6;
  const int l   = rem & 63;
  const int e   = nfg * 16 + (l & 15);
  const int kb  = ks * 32 + ((l >> 4) << 3);
  const float* src = &w[(size_t)e * D_DIM + kb];
  float f[8];
  *reinterpret_cast<float4*>(&f[0]) = *reinterpret_cast<const float4*>(src);
  *reinterpret_cast<float4*>(&f[4]) = *reinterpret_cast<const float4*>(src + 4);
  union { unsigned short s[8]; float4 v; } h[3];
  #pragma unroll
  for (int j = 0; j < 8; ++j) split3(f[j], h[0].s[j], h[1].s[j], h[2].s[j]);
  const size_t base = (size_t)ks * 24576 + (size_t)nfg * 512 + (size_t)l * 8;
  #pragma unroll
  for (int s = 0; s < 3; ++s)
    *reinterpret_cast<float4*>(wf + base + (size_t)s * 8192) = h[s].v;
}

// ---- fused GEMM (bf16x3 MFMA) + softmax + group-limited top-k routing ----
__global__ __launch_bounds__(NTHREADS, 1) void gate_kernel(
    const float* __restrict__ x,
    const unsigned short* __restrict__ wf,
    const float* __restrict__ bias,
    float* __restrict__ out_w,
    float* __restrict__ out_idx,
    float* __restrict__ out_load) {

  __shared__ SMem sm;
  __shared__ int hist[NEXP];

  const int tid  = threadIdx.x;
  const int row0 = blockIdx.x * BM;
  const int lane = tid & 63;
  const int wid  = tid >> 6;       // 0..7
  const int wr   = wid >> 2;       // wave row: 32 tokens
  const int wc   = wid & 3;        // wave col: 64 experts (nfg wc*4..wc*4+3)

  for (int i = tid; i < NEXP; i += NTHREADS) hist[i] = 0;

  // x staging map: thread -> (row, 4 consecutive k)
  const int srow = tid >> 3;            // 0..63
  const int kq   = (tid & 7) * 4;       // 0..28
  const float* xp = &x[(size_t)(row0 + srow) * D_DIM + kq];
  const int s_mfg  = srow >> 4;
  const int s_lane = ((kq >> 3) << 4) | (srow & 15);
  const int s_j    = kq & 4;

  f32x4 acc[2][4];
  #pragma unroll
  for (int i = 0; i < 2; ++i)
    #pragma unroll
    for (int j = 0; j < 4; ++j) acc[i][j] = (f32x4)(0.0f);

  float xv[4];

  // ---- prologue: stage step 0
  *reinterpret_cast<float4*>(xv) = *reinterpret_cast<const float4*>(xp);
  {
    Pack4 h[3];
    #pragma unroll
    for (int t = 0; t < 4; ++t) split3(xv[t], h[0].s[t], h[1].s[t], h[2].s[t]);
    #pragma unroll
    for (int s = 0; s < 3; ++s)
      *reinterpret_cast<float2*>(&sm.g.A[0][s][s_mfg][s_lane][s_j]) = h[s].v;
  }
  #pragma unroll
  for (int i = 0; i < 4; ++i) {            // B splits 0,1 : 32 chunks of 1KB
    const int c = wid * 4 + i;             // 0..31
    const int s = c >> 4, nfg = c & 15;
    __builtin_amdgcn_global_load_lds(
        (g_ushort*)(wf + (size_t)s * 8192 + (size_t)nfg * 512 + (size_t)lane * 8),
        (l_ushort*)&sm.g.B[0][s][nfg][0][0], 16, 0, 0);
  }
  __syncthreads();

  int cur = 0;
  for (int ks = 0; ks < KSTEPS; ++ks) {
    const bool more = (ks + 1 < KSTEPS);
    const size_t kb = (size_t)ks * 24576;

    // 1) b2 fragments for THIS step -> regs (L2-hot, oldest in vmcnt queue)
    float4 b2v[4];
    #pragma unroll
    for (int i = 0; i < 4; ++i)
      b2v[i] = *reinterpret_cast<const float4*>(
          wf + kb + 2 * 8192 + (size_t)(wc * 4 + i) * 512 + (size_t)lane * 8);

    // 2) x prefetch for NEXT step (HBM latency hides under MFMA)
    if (more)
      *reinterpret_cast<float4*>(xv) =
          *reinterpret_cast<const float4*>(xp + (ks + 1) * BK);

    // 3) async-stage B splits 0,1 for NEXT step
    if (more) {
      const int nxt = cur ^ 1;
      #pragma unroll
      for (int i = 0; i < 4; ++i) {
        const int c = wid * 4 + i;
        const int s = c >> 4, nfg = c & 15;
        __builtin_amdgcn_global_load_lds(
            (g_ushort*)(wf + kb + 24576 + (size_t)s * 8192 +
                        (size_t)nfg * 512 + (size_t)lane * 8),
            (l_ushort*)&sm.g.B[nxt][s][nfg][0][0], 16, 0, 0);
      }
    }

    // 4) MFMA: 6 split-products per (mf,nf); b2 product last
    {
      bf16x8 a[2][3];
      #pragma unroll
      for (int mf = 0; mf < 2; ++mf)
        #pragma unroll
        for (int s = 0; s < 3; ++s)
          a[mf][s] = *reinterpret_cast<const bf16x8*>(
              &sm.g.A[cur][s][wr * 2 + mf][lane][0]);
      #pragma unroll
      for (int nf = 0; nf < 4; ++nf) {
        const int nfg = wc * 4 + nf;
        bf16x8 b0 = *reinterpret_cast<const bf16x8*>(&sm.g.B[cur][0][nfg][lane][0]);
        bf16x8 b1 = *reinterpret_cast<const bf16x8*>(&sm.g.B[cur][1][nfg][lane][0]);
        bf16x8 b2 = *reinterpret_cast<const bf16x8*>(&b2v[nf]);
        #pragma unroll
        for (int mf = 0; mf < 2; ++mf) {
          f32x4 c = acc[mf][nf];
          c = __builtin_amdgcn_mfma_f32_16x16x32_bf16(a[mf][1], b1, c, 0, 0, 0);
          c = __builtin_amdgcn_mfma_f32_16x16x32_bf16(a[mf][2], b0, c, 0, 0, 0);
          c = __builtin_amdgcn_mfma_f32_16x16x32_bf16(a[mf][0], b1, c, 0, 0, 0);
          c = __builtin_amdgcn_mfma_f32_16x16x32_bf16(a[mf][1], b0, c, 0, 0, 0);
          c = __builtin_amdgcn_mfma_f32_16x16x32_bf16(a[mf][0], b0, c, 0, 0, 0);
          c = __builtin_amdgcn_mfma_f32_16x16x32_bf16(a[mf][0], b2, c, 0, 0, 0);
          acc[mf][nf] = c;
        }
      }
    }

    // 5) split x(next) -> A[next]
    if (more) {
      const int nxt = cur ^ 1;
      Pack4 h[3];
      #pragma unroll
      for (int t = 0; t < 4; ++t) split3(xv[t], h[0].s[t], h[1].s[t], h[2].s[t]);
      #pragma unroll
      for (int s = 0; s < 3; ++s)
        *reinterpret_cast<float2*>(&sm.g.A[nxt][s][s_mfg][s_lane][s_j]) = h[s].v;
    }
    __syncthreads();
    cur ^= 1;
  }

  // ---- epilogue: logits -> Sc (C/D layout: col=lane&15, row=(lane>>4)*4+r)
  #pragma unroll
  for (int mf = 0; mf < 2; ++mf)
    #pragma unroll
    for (int nf = 0; nf < 4; ++nf)
      #pragma unroll
      for (int r = 0; r < 4; ++r) {
        const int row = wr * 32 + mf * 16 + ((lane >> 4) << 2) + r;
        const int col = wc * 64 + nf * 16 + (lane & 15);
        sm.Sc[row][col] = acc[mf][nf][r];
      }
  __syncthreads();

  // ---- routing: one wave per token, lane holds experts 4l..4l+3
  const float4 bsl = *reinterpret_cast<const float4*>(&bias[lane * 4]);
  const int g = lane >> 3;   // group of this lane's experts

  for (int m = wid; m < BM; m += 8) {
    float v[4];
    *reinterpret_cast<float4*>(v) =
        *reinterpret_cast<const float4*>(&sm.Sc[m][lane * 4]);

    // softmax (match jax: subtract row max, exp, divide by sum)
    float mx = fmaxf(fmaxf(v[0], v[1]), fmaxf(v[2], v[3]));
    #pragma unroll
    for (int s = 1; s < 64; s <<= 1) mx = fmaxf(mx, __shfl_xor(mx, s));
    float ex[4], sum = 0.f;
    #pragma unroll
    for (int j = 0; j < 4; ++j) { ex[j] = expf(v[j] - mx); sum += ex[j]; }
    #pragma unroll
    for (int s = 1; s < 64; s <<= 1) sum += __shfl_xor(sum, s);
    float sc[4], sel[4];
    sc[0] = ex[0] / sum; sc[1] = ex[1] / sum;
    sc[2] = ex[2] / sum; sc[3] = ex[3] / sum;
    sel[0] = sc[0] + bsl.x; sel[1] = sc[1] + bsl.y;
    sel[2] = sc[2] + bsl.z; sel[3] = sc[3] + bsl.w;

    // keep original scores for the gather
    *reinterpret_cast<float4*>(&sm.Sc[m][lane * 4]) =
        make_float4(sc[0], sc[1], sc[2], sc[3]);

    // group max (groups of 32 experts = 8 lanes)
    float gv = fmaxf(fmaxf(sel[0], sel[1]), fmaxf(sel[2], sel[3]));
    gv = fmaxf(gv, __shfl_xor(gv, 1));
    gv = fmaxf(gv, __shfl_xor(gv, 2));
    gv = fmaxf(gv, __shfl_xor(gv, 4));

    // top-4 groups, tie -> lower group index (jax.lax.top_k stability)
    unsigned gmask = 0;
    float gcur = gv;
    #pragma unroll
    for (int it = 0; it < NLIM; ++it) {
      float bv2 = gcur; int bi = g;
      #pragma unroll
      for (int s = 1; s < 64; s <<= 1) {
        float ov = __shfl_xor(bv2, s);
        int   oi = __shfl_xor(bi, s);
        if (ov > bv2 || (ov == bv2 && oi < bi)) { bv2 = ov; bi = oi; }
      }
      gmask |= 1u << bi;
      if (g == bi) gcur = -INFINITY;
    }
    if (!((gmask >> g) & 1u)) {
      sel[0] = sel[1] = sel[2] = sel[3] = -INFINITY;
    }

    // top-8 experts, tie -> lower expert index
    const int gtok = row0 + m;
    #pragma unroll
    for (int it = 0; it < TOPK; ++it) {
      float bv2 = sel[0]; int bi = lane * 4;
      #pragma unroll
      for (int j = 1; j < 4; ++j)
        if (sel[j] > bv2) { bv2 = sel[j]; bi = lane * 4 + j; }
      #pragma unroll
      for (int s = 1; s < 64; s <<= 1) {
        float ov = __shfl_xor(bv2, s);
        int   oi = __shfl_xor(bi, s);
        if (ov > bv2 || (ov == bv2 && oi < bi)) { bv2 = ov; bi = oi; }
      }
      if (lane == 0) {
        out_w[(size_t)gtok * TOPK + it]   = sm.Sc[m][bi] * 2.5f;
        out_idx[(size_t)gtok * TOPK + it] = (float)bi;
        atomicAdd(&hist[bi], 1);
      }
      if ((bi >> 2) == lane) sel[bi & 3] = -INFINITY;
    }
  }

  __syncthreads();
  for (int b = tid; b < NEXP; b += NTHREADS)
    if (hist[b]) atomicAdd(&out_load[b], (float)hist[b]);
}

extern "C" void kernel_launch(void* const* d_in, const int* in_sizes, int n_in,
                              void* d_out, int out_size, void* d_ws, size_t ws_size,
                              hipStream_t stream) {
  const float* x    = (const float*)d_in[0];
  const float* w    = (const float*)d_in[1];
  const float* bias = (const float*)d_in[2];
  float* out_w    = (float*)d_out;
  float* out_idx  = out_w + (size_t)T_TOKENS * TOPK;
  float* out_load = out_idx + (size_t)T_TOKENS * TOPK;
  unsigned short* wfrag = (unsigned short*)d_ws;   // 3 MB fragment-ordered w splits

  hipMemsetAsync(out_load, 0, NEXP * sizeof(float), stream);
  prep_w<<<256, 256, 0, stream>>>(w, wfrag);
  gate_kernel<<<T_TOKENS / BM, NTHREADS, 0, stream>>>(
      x, wfrag, bias, out_w, out_idx, out_load);
}

// Round 5
// 240.144 us; speedup vs baseline: 2.7864x; 1.0696x over previous
//
#include <hip/hip_runtime.h>
#include <math.h>

#define T_TOKENS 16384
#define D_DIM    2048
#define NEXP     256
#define TOPK     8
#define NLIM     4
#define BM       64
#define BK       32
#define KSTEPS   (D_DIM / BK)   // 64
#define NTHREADS 512

typedef __attribute__((ext_vector_type(8))) short bf16x8;   // 8 bf16 (4 VGPRs)
typedef __attribute__((ext_vector_type(4))) float f32x4;    // MFMA acc

struct BFrag { union { float4 f4; bf16x8 bf; }; };

__device__ __forceinline__ void split3b(float f, unsigned& h0, unsigned& h1,
                                        unsigned& h2) {
  unsigned u = __float_as_uint(f);
  h0 = (u + 0x7FFFu + ((u >> 16) & 1u)) >> 16;            // RTN-even bf16
  float r = f - __uint_as_float(h0 << 16);
  u = __float_as_uint(r);
  h1 = (u + 0x7FFFu + ((u >> 16) & 1u)) >> 16;
  float r2 = r - __uint_as_float(h1 << 16);
  u = __float_as_uint(r2);
  h2 = (u + 0x7FFFu + ((u >> 16) & 1u)) >> 16;
}

// ---- pre-pass: w[256][2048] f32 -> 3 bf16 splits in MFMA-fragment order ----
// wf layout (bf16 elems): [ks(64)][split(3)][nfg(16)][lane(64)][j(8)]
// value = split_s( w[ e = nfg*16 + (lane&15) ][ k = ks*32 + (lane>>4)*8 + j ] )
__global__ __launch_bounds__(256) void prep_w(const float* __restrict__ w,
                                              unsigned short* __restrict__ wf) {
  const int g   = blockIdx.x * 256 + threadIdx.x;  // 0..65535
  const int ks  = g >> 10;
  const int rem = g & 1023;
  const int nfg = rem >> 6;
  const int l   = rem & 63;
  const int e   = nfg * 16 + (l & 15);
  const int kb  = ks * 32 + ((l >> 4) << 3);
  const float* src = &w[(size_t)e * D_DIM + kb];
  float f[8];
  *reinterpret_cast<float4*>(&f[0]) = *reinterpret_cast<const float4*>(src);
  *reinterpret_cast<float4*>(&f[4]) = *reinterpret_cast<const float4*>(src + 4);
  union { unsigned u[4]; float4 v; } h[3];
  #pragma unroll
  for (int q = 0; q < 4; ++q) {
    unsigned lo0, lo1, lo2, hi0, hi1, hi2;
    split3b(f[2 * q],     lo0, lo1, lo2);
    split3b(f[2 * q + 1], hi0, hi1, hi2);
    h[0].u[q] = lo0 | (hi0 << 16);
    h[1].u[q] = lo1 | (hi1 << 16);
    h[2].u[q] = lo2 | (hi2 << 16);
  }
  const size_t base = (size_t)ks * 24576 + (size_t)nfg * 512 + (size_t)l * 8;
  #pragma unroll
  for (int s = 0; s < 3; ++s)
    *reinterpret_cast<float4*>(wf + base + (size_t)s * 8192) = h[s].v;
}

// ---- one K-step: prefetch (ks+1) into (bn,xn), compute ks from (bc,xc) ----
__device__ __forceinline__ void k_step(
    int ks, const float* xp0, const float* xp1, const unsigned short* wfl,
    BFrag (&bc)[12], float4 (&xc)[4],
    BFrag (&bn)[12], float4 (&xn)[4],
    f32x4 (&acc)[2][4]) {
  const int kn = (ks + 1 < KSTEPS) ? ks + 1 : KSTEPS - 1;

  // prefetch next-step B fragments (L2-hot, fragment-linear in wf)
  #pragma unroll
  for (int s = 0; s < 3; ++s)
    #pragma unroll
    for (int nf = 0; nf < 4; ++nf)
      bn[s * 4 + nf].f4 = *reinterpret_cast<const float4*>(
          wfl + (size_t)kn * 24576 + s * 8192 + nf * 512);
  // prefetch next-step A raw floats (HBM)
  xn[0] = *reinterpret_cast<const float4*>(xp0 + kn * BK);
  xn[1] = *reinterpret_cast<const float4*>(xp0 + kn * BK + 4);
  xn[2] = *reinterpret_cast<const float4*>(xp1 + kn * BK);
  xn[3] = *reinterpret_cast<const float4*>(xp1 + kn * BK + 4);

  // split current x (loaded a full step ago) into 3 bf16 A-fragments per mf
  bf16x8 af[2][3];
  #pragma unroll
  for (int mf = 0; mf < 2; ++mf) {
    float xf[8];
    *reinterpret_cast<float4*>(&xf[0]) = xc[mf * 2 + 0];
    *reinterpret_cast<float4*>(&xf[4]) = xc[mf * 2 + 1];
    union { unsigned u[4]; bf16x8 v; } h0, h1, h2;
    #pragma unroll
    for (int q = 0; q < 4; ++q) {
      unsigned lo0, lo1, lo2, hi0, hi1, hi2;
      split3b(xf[2 * q],     lo0, lo1, lo2);
      split3b(xf[2 * q + 1], hi0, hi1, hi2);
      h0.u[q] = lo0 | (hi0 << 16);
      h1.u[q] = lo1 | (hi1 << 16);
      h2.u[q] = lo2 | (hi2 << 16);
    }
    af[mf][0] = h0.v; af[mf][1] = h1.v; af[mf][2] = h2.v;
  }

  // 6 split-products per (mf,nf) accumulator
  #pragma unroll
  for (int nf = 0; nf < 4; ++nf) {
    bf16x8 b0 = bc[0 * 4 + nf].bf;
    bf16x8 b1 = bc[1 * 4 + nf].bf;
    bf16x8 b2 = bc[2 * 4 + nf].bf;
    #pragma unroll
    for (int mf = 0; mf < 2; ++mf) {
      f32x4 c = acc[mf][nf];
      c = __builtin_amdgcn_mfma_f32_16x16x32_bf16(af[mf][1], b1, c, 0, 0, 0);
      c = __builtin_amdgcn_mfma_f32_16x16x32_bf16(af[mf][2], b0, c, 0, 0, 0);
      c = __builtin_amdgcn_mfma_f32_16x16x32_bf16(af[mf][0], b1, c, 0, 0, 0);
      c = __builtin_amdgcn_mfma_f32_16x16x32_bf16(af[mf][1], b0, c, 0, 0, 0);
      c = __builtin_amdgcn_mfma_f32_16x16x32_bf16(af[mf][0], b0, c, 0, 0, 0);
      c = __builtin_amdgcn_mfma_f32_16x16x32_bf16(af[mf][0], b2, c, 0, 0, 0);
      acc[mf][nf] = c;
    }
  }
}

// ---- fused GEMM (bf16x3 MFMA, register-resident, no K-loop barriers) ----
__global__ __launch_bounds__(NTHREADS, 2) void gate_kernel(
    const float* __restrict__ x,
    const unsigned short* __restrict__ wf,
    const float* __restrict__ bias,
    float* __restrict__ out_w,
    float* __restrict__ out_idx,
    float* __restrict__ out_load) {

  __shared__ float Sc[BM][NEXP];
  __shared__ int hist[NEXP];

  const int tid  = threadIdx.x;
  const int row0 = blockIdx.x * BM;
  const int lane = tid & 63;
  const int wid  = tid >> 6;   // 0..7
  const int wr   = wid >> 2;   // wave row: 32 tokens (2 mf tiles)
  const int wc   = wid & 3;    // wave col: 64 experts (nfg wc*4..wc*4+3)

  for (int i = tid; i < NEXP; i += NTHREADS) hist[i] = 0;

  // per-lane A source: row = row0 + wr*32 + mf*16 + (lane&15),
  //                    k   = ks*32 + (lane>>4)*8 + j
  const int xrow = row0 + wr * 32 + (lane & 15);
  const float* xp0 = &x[(size_t)xrow * D_DIM + ((lane >> 4) << 3)];
  const float* xp1 = xp0 + (size_t)16 * D_DIM;
  // per-lane B source base (fragment-linear wf)
  const unsigned short* wfl = wf + (size_t)(wc * 4) * 512 + (size_t)lane * 8;

  f32x4 acc[2][4];
  #pragma unroll
  for (int i = 0; i < 2; ++i)
    #pragma unroll
    for (int j = 0; j < 4; ++j) acc[i][j] = (f32x4)(0.0f);

  BFrag bA[12], bB[12];
  float4 xA[4], xB[4];

  // prologue: load step 0
  #pragma unroll
  for (int s = 0; s < 3; ++s)
    #pragma unroll
    for (int nf = 0; nf < 4; ++nf)
      bA[s * 4 + nf].f4 = *reinterpret_cast<const float4*>(
          wfl + (size_t)s * 8192 + nf * 512);
  xA[0] = *reinterpret_cast<const float4*>(xp0);
  xA[1] = *reinterpret_cast<const float4*>(xp0 + 4);
  xA[2] = *reinterpret_cast<const float4*>(xp1);
  xA[3] = *reinterpret_cast<const float4*>(xp1 + 4);

  for (int ks = 0; ks < KSTEPS; ks += 2) {
    k_step(ks,     xp0, xp1, wfl, bA, xA, bB, xB, acc);
    k_step(ks + 1, xp0, xp1, wfl, bB, xB, bA, xA, acc);
  }

  // ---- epilogue: logits -> Sc (C/D layout: col=lane&15, row=(lane>>4)*4+r)
  #pragma unroll
  for (int mf = 0; mf < 2; ++mf)
    #pragma unroll
    for (int nf = 0; nf < 4; ++nf)
      #pragma unroll
      for (int r = 0; r < 4; ++r) {
        const int row = wr * 32 + mf * 16 + ((lane >> 4) << 2) + r;
        const int col = wc * 64 + nf * 16 + (lane & 15);
        Sc[row][col] = acc[mf][nf][r];
      }
  __syncthreads();

  // ---- routing: one wave per token, lane holds experts 4l..4l+3
  const float4 bsl = *reinterpret_cast<const float4*>(&bias[lane * 4]);
  const int g = lane >> 3;   // group of this lane's experts

  for (int m = wid; m < BM; m += 8) {
    float v[4];
    *reinterpret_cast<float4*>(v) =
        *reinterpret_cast<const float4*>(&Sc[m][lane * 4]);

    // softmax (match jax: subtract row max, exp, divide by sum)
    float mx = fmaxf(fmaxf(v[0], v[1]), fmaxf(v[2], v[3]));
    #pragma unroll
    for (int s = 1; s < 64; s <<= 1) mx = fmaxf(mx, __shfl_xor(mx, s));
    float ex[4], sum = 0.f;
    #pragma unroll
    for (int j = 0; j < 4; ++j) { ex[j] = expf(v[j] - mx); sum += ex[j]; }
    #pragma unroll
    for (int s = 1; s < 64; s <<= 1) sum += __shfl_xor(sum, s);
    float sc[4], sel[4];
    sc[0] = ex[0] / sum; sc[1] = ex[1] / sum;
    sc[2] = ex[2] / sum; sc[3] = ex[3] / sum;
    sel[0] = sc[0] + bsl.x; sel[1] = sc[1] + bsl.y;
    sel[2] = sc[2] + bsl.z; sel[3] = sc[3] + bsl.w;

    // keep original scores for the gather
    *reinterpret_cast<float4*>(&Sc[m][lane * 4]) =
        make_float4(sc[0], sc[1], sc[2], sc[3]);

    // group max (groups of 32 experts = 8 lanes)
    float gv = fmaxf(fmaxf(sel[0], sel[1]), fmaxf(sel[2], sel[3]));
    gv = fmaxf(gv, __shfl_xor(gv, 1));
    gv = fmaxf(gv, __shfl_xor(gv, 2));
    gv = fmaxf(gv, __shfl_xor(gv, 4));

    // top-4 groups, tie -> lower group index (jax.lax.top_k stability)
    unsigned gmask = 0;
    float gcur = gv;
    #pragma unroll
    for (int it = 0; it < NLIM; ++it) {
      float bv2 = gcur; int bi = g;
      #pragma unroll
      for (int s = 1; s < 64; s <<= 1) {
        float ov = __shfl_xor(bv2, s);
        int   oi = __shfl_xor(bi, s);
        if (ov > bv2 || (ov == bv2 && oi < bi)) { bv2 = ov; bi = oi; }
      }
      gmask |= 1u << bi;
      if (g == bi) gcur = -INFINITY;
    }
    if (!((gmask >> g) & 1u)) {
      sel[0] = sel[1] = sel[2] = sel[3] = -INFINITY;
    }

    // top-8 experts, tie -> lower expert index
    const int gtok = row0 + m;
    #pragma unroll
    for (int it = 0; it < TOPK; ++it) {
      float bv2 = sel[0]; int bi = lane * 4;
      #pragma unroll
      for (int j = 1; j < 4; ++j)
        if (sel[j] > bv2) { bv2 = sel[j]; bi = lane * 4 + j; }
      #pragma unroll
      for (int s = 1; s < 64; s <<= 1) {
        float ov = __shfl_xor(bv2, s);
        int   oi = __shfl_xor(bi, s);
        if (ov > bv2 || (ov == bv2 && oi < bi)) { bv2 = ov; bi = oi; }
      }
      if (lane == 0) {
        out_w[(size_t)gtok * TOPK + it]   = Sc[m][bi] * 2.5f;
        out_idx[(size_t)gtok * TOPK + it] = (float)bi;
        atomicAdd(&hist[bi], 1);
      }
      if ((bi >> 2) == lane) sel[bi & 3] = -INFINITY;
    }
  }

  __syncthreads();
  for (int b = tid; b < NEXP; b += NTHREADS)
    if (hist[b]) atomicAdd(&out_load[b], (float)hist[b]);
}

extern "C" void kernel_launch(void* const* d_in, const int* in_sizes, int n_in,
                              void* d_out, int out_size, void* d_ws, size_t ws_size,
                              hipStream_t stream) {
  const float* x    = (const float*)d_in[0];
  const float* w    = (const float*)d_in[1];
  const float* bias = (const float*)d_in[2];
  float* out_w    = (float*)d_out;
  float* out_idx  = out_w + (size_t)T_TOKENS * TOPK;
  float* out_load = out_idx + (size_t)T_TOKENS * TOPK;
  unsigned short* wfrag = (unsigned short*)d_ws;   // 3 MB fragment-ordered w splits

  hipMemsetAsync(out_load, 0, NEXP * sizeof(float), stream);
  prep_w<<<256, 256, 0, stream>>>(w, wfrag);
  gate_kernel<<<T_TOKENS / BM, NTHREADS, 0, stream>>>(
      x, wfrag, bias, out_w, out_idx, out_load);
}

// Round 6
// 170.020 us; speedup vs baseline: 3.9357x; 1.4124x over previous
//
#include <hip/hip_runtime.h>
#include <math.h>

#define T_TOKENS 16384
#define D_DIM    2048
#define NEXP     256
#define TOPK     8
#define NLIM     4
#define BM       32
#define BK       32
#define KSTEPS   (D_DIM / BK)   // 64
#define NTHREADS 512

typedef __attribute__((ext_vector_type(8))) short bf16x8;   // 8 bf16 (4 VGPRs)
typedef __attribute__((ext_vector_type(4))) float f32x4;    // MFMA acc

struct BFrag { union { float4 f4; bf16x8 bf; }; };

__device__ __forceinline__ unsigned rtn_hi(float f) {  // RTN-even bf16 in hi16
  unsigned u = __float_as_uint(f);
  return (u + 0x7FFFu + ((u >> 16) & 1u)) & 0xFFFF0000u;
}

// split x = a0 + a1 (+eps, eps <= 2^-18|x|), both RTN-even bf16
__device__ __forceinline__ void split2b(float f, unsigned& h0, unsigned& h1) {
  h0 = rtn_hi(f);
  float r = f - __uint_as_float(h0);
  h1 = rtn_hi(r);
}

// ---- pre-pass: w[256][2048] f32 -> 2 bf16 splits in MFMA-fragment order ----
// wf layout (bf16 elems): [ks(64)][split(2)][nfg(16)][lane(64)][j(8)]
// value = split_s( w[ e = nfg*16 + (lane&15) ][ k = ks*32 + (lane>>4)*8 + j ] )
__global__ __launch_bounds__(256) void prep_w(const float* __restrict__ w,
                                              unsigned short* __restrict__ wf) {
  const int g   = blockIdx.x * 256 + threadIdx.x;  // 0..65535
  const int ks  = g >> 10;
  const int rem = g & 1023;
  const int nfg = rem >> 6;
  const int l   = rem & 63;
  const int e   = nfg * 16 + (l & 15);
  const int kb  = ks * 32 + ((l >> 4) << 3);
  const float* src = &w[(size_t)e * D_DIM + kb];
  float f[8];
  *reinterpret_cast<float4*>(&f[0]) = *reinterpret_cast<const float4*>(src);
  *reinterpret_cast<float4*>(&f[4]) = *reinterpret_cast<const float4*>(src + 4);
  union { unsigned u[4]; float4 v; } h[2];
  #pragma unroll
  for (int q = 0; q < 4; ++q) {
    unsigned lo0, lo1, hi0, hi1;
    split2b(f[2 * q],     lo0, lo1);
    split2b(f[2 * q + 1], hi0, hi1);
    h[0].u[q] = (lo0 >> 16) | hi0;
    h[1].u[q] = (lo1 >> 16) | hi1;
  }
  const size_t base = (size_t)ks * 16384 + (size_t)nfg * 512 + (size_t)l * 8;
  *reinterpret_cast<float4*>(wf + base)        = h[0].v;
  *reinterpret_cast<float4*>(wf + base + 8192) = h[1].v;
}

// ---- one K-step: prefetch (ks+1) into (bn,xn), compute ks from (bc,xc) ----
__device__ __forceinline__ void k_step(
    int ks, const float* xp, const unsigned short* wfl,
    BFrag (&bc)[8], float4 (&xc)[2],
    BFrag (&bn)[8], float4 (&xn)[2],
    f32x4 (&acc)[4]) {
  const int kn = (ks + 1 < KSTEPS) ? ks + 1 : KSTEPS - 1;

  // prefetch next-step B fragments (L2-hot, fragment-linear in wf)
  #pragma unroll
  for (int s = 0; s < 2; ++s)
    #pragma unroll
    for (int nf = 0; nf < 4; ++nf)
      bn[s * 4 + nf].f4 = *reinterpret_cast<const float4*>(
          wfl + (size_t)kn * 16384 + s * 8192 + nf * 512);
  // prefetch next-step A raw floats
  xn[0] = *reinterpret_cast<const float4*>(xp + kn * BK);
  xn[1] = *reinterpret_cast<const float4*>(xp + kn * BK + 4);

  // split current x into 2 bf16 A-fragments
  bf16x8 a0, a1;
  {
    float xf[8];
    *reinterpret_cast<float4*>(&xf[0]) = xc[0];
    *reinterpret_cast<float4*>(&xf[4]) = xc[1];
    union { unsigned u[4]; bf16x8 v; } h0, h1;
    #pragma unroll
    for (int q = 0; q < 4; ++q) {
      unsigned lo0, lo1, hi0, hi1;
      split2b(xf[2 * q],     lo0, lo1);
      split2b(xf[2 * q + 1], hi0, hi1);
      h0.u[q] = (lo0 >> 16) | hi0;
      h1.u[q] = (lo1 >> 16) | hi1;
    }
    a0 = h0.v; a1 = h1.v;
  }

  // 3 split-products per nf accumulator
  #pragma unroll
  for (int nf = 0; nf < 4; ++nf) {
    bf16x8 b0 = bc[0 * 4 + nf].bf;
    bf16x8 b1 = bc[1 * 4 + nf].bf;
    f32x4 c = acc[nf];
    c = __builtin_amdgcn_mfma_f32_16x16x32_bf16(a1, b0, c, 0, 0, 0);
    c = __builtin_amdgcn_mfma_f32_16x16x32_bf16(a0, b1, c, 0, 0, 0);
    c = __builtin_amdgcn_mfma_f32_16x16x32_bf16(a0, b0, c, 0, 0, 0);
    acc[nf] = c;
  }
}

// ---- fused GEMM (bf16x2 MFMA, register-resident, no K-loop barriers) ----
__global__ __launch_bounds__(NTHREADS, 4) void gate_kernel(
    const float* __restrict__ x,
    const unsigned short* __restrict__ wf,
    const float* __restrict__ bias,
    float* __restrict__ out_w,
    float* __restrict__ out_idx,
    float* __restrict__ out_load) {

  __shared__ float Sc[BM][NEXP];
  __shared__ int hist[NEXP];

  const int tid  = threadIdx.x;
  const int row0 = blockIdx.x * BM;
  const int lane = tid & 63;
  const int wid  = tid >> 6;   // 0..7
  const int wr   = wid >> 2;   // wave row: 16 tokens
  const int wc   = wid & 3;    // wave col: 64 experts (nfg wc*4..wc*4+3)

  for (int i = tid; i < NEXP; i += NTHREADS) hist[i] = 0;

  // per-lane A source: row = row0 + wr*16 + (lane&15), k = ks*32+(lane>>4)*8+j
  const int xrow = row0 + wr * 16 + (lane & 15);
  const float* xp = &x[(size_t)xrow * D_DIM + ((lane >> 4) << 3)];
  // per-lane B source base (fragment-linear wf)
  const unsigned short* wfl = wf + (size_t)(wc * 4) * 512 + (size_t)lane * 8;

  f32x4 acc[4];
  #pragma unroll
  for (int j = 0; j < 4; ++j) acc[j] = (f32x4)(0.0f);

  BFrag bA[8], bB[8];
  float4 xA[2], xB[2];

  // prologue: load step 0
  #pragma unroll
  for (int s = 0; s < 2; ++s)
    #pragma unroll
    for (int nf = 0; nf < 4; ++nf)
      bA[s * 4 + nf].f4 = *reinterpret_cast<const float4*>(
          wfl + (size_t)s * 8192 + nf * 512);
  xA[0] = *reinterpret_cast<const float4*>(xp);
  xA[1] = *reinterpret_cast<const float4*>(xp + 4);

  for (int ks = 0; ks < KSTEPS; ks += 2) {
    k_step(ks,     xp, wfl, bA, xA, bB, xB, acc);
    k_step(ks + 1, xp, wfl, bB, xB, bA, xA, acc);
  }

  // ---- epilogue: logits -> Sc (C/D layout: col=lane&15, row=(lane>>4)*4+r)
  #pragma unroll
  for (int nf = 0; nf < 4; ++nf)
    #pragma unroll
    for (int r = 0; r < 4; ++r) {
      const int row = wr * 16 + ((lane >> 4) << 2) + r;
      const int col = wc * 64 + nf * 16 + (lane & 15);
      Sc[row][col] = acc[nf][r];
    }
  __syncthreads();

  // ---- routing: one wave per token, lane holds experts 4l..4l+3
  const float4 bsl = *reinterpret_cast<const float4*>(&bias[lane * 4]);
  const int g = lane >> 3;   // group of this lane's experts

  for (int m = wid; m < BM; m += 8) {
    float v[4];
    *reinterpret_cast<float4*>(v) =
        *reinterpret_cast<const float4*>(&Sc[m][lane * 4]);

    // softmax (match jax: subtract row max, exp, divide by sum)
    float mx = fmaxf(fmaxf(v[0], v[1]), fmaxf(v[2], v[3]));
    #pragma unroll
    for (int s = 1; s < 64; s <<= 1) mx = fmaxf(mx, __shfl_xor(mx, s));
    float ex[4], sum = 0.f;
    #pragma unroll
    for (int j = 0; j < 4; ++j) { ex[j] = expf(v[j] - mx); sum += ex[j]; }
    #pragma unroll
    for (int s = 1; s < 64; s <<= 1) sum += __shfl_xor(sum, s);
    float sc[4], sel[4];
    sc[0] = ex[0] / sum; sc[1] = ex[1] / sum;
    sc[2] = ex[2] / sum; sc[3] = ex[3] / sum;
    sel[0] = sc[0] + bsl.x; sel[1] = sc[1] + bsl.y;
    sel[2] = sc[2] + bsl.z; sel[3] = sc[3] + bsl.w;

    // keep original scores for the gather
    *reinterpret_cast<float4*>(&Sc[m][lane * 4]) =
        make_float4(sc[0], sc[1], sc[2], sc[3]);

    // group max (groups of 32 experts = 8 lanes)
    float gv = fmaxf(fmaxf(sel[0], sel[1]), fmaxf(sel[2], sel[3]));
    gv = fmaxf(gv, __shfl_xor(gv, 1));
    gv = fmaxf(gv, __shfl_xor(gv, 2));
    gv = fmaxf(gv, __shfl_xor(gv, 4));

    // top-4 groups, tie -> lower group index (jax.lax.top_k stability)
    unsigned gmask = 0;
    float gcur = gv;
    #pragma unroll
    for (int it = 0; it < NLIM; ++it) {
      float bv2 = gcur; int bi = g;
      #pragma unroll
      for (int s = 1; s < 64; s <<= 1) {
        float ov = __shfl_xor(bv2, s);
        int   oi = __shfl_xor(bi, s);
        if (ov > bv2 || (ov == bv2 && oi < bi)) { bv2 = ov; bi = oi; }
      }
      gmask |= 1u << bi;
      if (g == bi) gcur = -INFINITY;
    }
    if (!((gmask >> g) & 1u)) {
      sel[0] = sel[1] = sel[2] = sel[3] = -INFINITY;
    }

    // top-8 experts, tie -> lower expert index
    const int gtok = row0 + m;
    #pragma unroll
    for (int it = 0; it < TOPK; ++it) {
      float bv2 = sel[0]; int bi = lane * 4;
      #pragma unroll
      for (int j = 1; j < 4; ++j)
        if (sel[j] > bv2) { bv2 = sel[j]; bi = lane * 4 + j; }
      #pragma unroll
      for (int s = 1; s < 64; s <<= 1) {
        float ov = __shfl_xor(bv2, s);
        int   oi = __shfl_xor(bi, s);
        if (ov > bv2 || (ov == bv2 && oi < bi)) { bv2 = ov; bi = oi; }
      }
      if (lane == 0) {
        out_w[(size_t)gtok * TOPK + it]   = Sc[m][bi] * 2.5f;
        out_idx[(size_t)gtok * TOPK + it] = (float)bi;
        atomicAdd(&hist[bi], 1);
      }
      if ((bi >> 2) == lane) sel[bi & 3] = -INFINITY;
    }
  }

  __syncthreads();
  for (int b = tid; b < NEXP; b += NTHREADS)
    if (hist[b]) atomicAdd(&out_load[b], (float)hist[b]);
}

extern "C" void kernel_launch(void* const* d_in, const int* in_sizes, int n_in,
                              void* d_out, int out_size, void* d_ws, size_t ws_size,
                              hipStream_t stream) {
  const float* x    = (const float*)d_in[0];
  const float* w    = (const float*)d_in[1];
  const float* bias = (const float*)d_in[2];
  float* out_w    = (float*)d_out;
  float* out_idx  = out_w + (size_t)T_TOKENS * TOPK;
  float* out_load = out_idx + (size_t)T_TOKENS * TOPK;
  unsigned short* wfrag = (unsigned short*)d_ws;   // 2 MB fragment-ordered w splits

  hipMemsetAsync(out_load, 0, NEXP * sizeof(float), stream);
  prep_w<<<256, 256, 0, stream>>>(w, wfrag);
  gate_kernel<<<T_TOKENS / BM, NTHREADS, 0, stream>>>(
      x, wfrag, bias, out_w, out_idx, out_load);
}